// Round 1
// baseline (404.345 us; speedup 1.0000x reference)
//
#include <hip/hip_runtime.h>

#define TOK 65536
#define DM 256
#define DF 1024
#define NB 4

typedef unsigned short ushort_t;
typedef unsigned int uint32;

typedef __attribute__((ext_vector_type(8))) short bf16x8;
typedef __attribute__((ext_vector_type(4))) float f32x4;
typedef __attribute__((ext_vector_type(4))) uint32 u32x4;

__device__ inline ushort_t f2bf(float f) {
  union { float f; unsigned int u; } v; v.f = f;
  unsigned int u = v.u;
  unsigned int r = (u + 0x7FFFu + ((u >> 16) & 1u)) >> 16;
  return (ushort_t)r;
}
__device__ inline float bf2f(ushort_t u) {
  union { unsigned int u; float f; } v; v.u = ((uint32)u) << 16; return v.f;
}
__device__ inline uint32 pack2(float a, float b) {
  return (uint32)f2bf(a) | ((uint32)f2bf(b) << 16);
}

// async global->LDS DMA, 16 B/lane: LDS dest = wave-uniform base + lane*16.
__device__ __forceinline__ void dma16(const ushort_t* g, ushort_t* lds) {
  __builtin_amdgcn_global_load_lds(
      (const __attribute__((address_space(1))) unsigned int*)(const void*)g,
      (__attribute__((address_space(3))) unsigned int*)(void*)lds,
      16, 0, 0);
}

// ---------------- kernel 0: convert w1/w2 fp32 -> bf16 + zero counts --------
__global__ __launch_bounds__(256) void prep_weights_kernel(
    const float* __restrict__ w1, const float* __restrict__ w2,
    ushort_t* __restrict__ w1b, ushort_t* __restrict__ w2b,
    int* __restrict__ counts)
{
  if (blockIdx.x == 0 && blockIdx.y == 0 && threadIdx.x < NB)
    counts[threadIdx.x] = 0;
  const int idx = blockIdx.x * 256 + threadIdx.x;
  const float* src = blockIdx.y ? w2 : w1;
  ushort_t* dst = blockIdx.y ? w2b : w1b;
  f32x4 v = *(const f32x4*)(src + (size_t)idx * 4);
  uint2 p;
  p.x = pack2(v.x, v.y);
  p.y = pack2(v.z, v.w);
  *(uint2*)(dst + (size_t)idx * 4) = p;
}

// ---------------- kernel 1: route tokens to per-branch lists + zero-fill ----
__global__ __launch_bounds__(256) void route_kernel(
    const int* __restrict__ b_seq, int* __restrict__ counts,
    ushort_t* __restrict__ lists, u32x4* __restrict__ out16)
{
  __shared__ int s_lpos[NB];
  __shared__ int s_lbase[NB];
  __shared__ int s_b[256];
  const int tid = threadIdx.x;
  const int base = blockIdx.x * 256;
  const int token = base + tid;
  if (tid < NB) s_lpos[tid] = 0;
  __syncthreads();
  const int b = b_seq[token];
  s_b[tid] = b;
  int my = 0;
  if (b > 0) my = atomicAdd(&s_lpos[b - 1], 1);
  __syncthreads();
  if (tid < NB) s_lbase[tid] = atomicAdd(&counts[tid], s_lpos[tid]);
  __syncthreads();
  if (b > 0) lists[(b - 1) * TOK + s_lbase[b - 1] + my] = (ushort_t)token;
  // zero-fill rows with b==0, 16 B per store (64 u32x4 per row of 256 f32)
  const u32x4 z = (u32x4){0u, 0u, 0u, 0u};
  #pragma unroll 4
  for (int it = 0; it < 64; ++it) {
    int flat = it * 256 + tid;
    int tl = flat >> 6;          // wave-uniform row
    int j = flat & 63;
    if (s_b[tl] == 0) out16[(size_t)(base + tl) * 64 + j] = z;
  }
}

// ---------------- kernel 2: fused FFN + LN, pipelined DMA, raw barriers -----
// Block = 6 waves (384 thr), M=96 tokens, 32 chunks of F=32.
// Occupancy plan: LDS 77,952 B -> 2 blocks/CU; __launch_bounds__(384,3) caps
// unified regs at 168 (arch ~104 + 64 acc) -> 12 waves/CU (3/SIMD), up from 8.
// GEMM1: wave (fi=wv&1, mh=wv>>1 in [0,3)) computes H[32 tok x 16 f].
// GEMM2: wave (dh=wv&1, mh)               computes Y[32 tok x 128 d].
// Weights double-buffered in LDS via global_load_lds issued one chunk ahead;
// entry barrier drains vmcnt(0)+lgkmcnt(0); mid barrier drains lgkm only so
// the prefetch is never force-drained mid-chunk.
__global__ __launch_bounds__(384, 3) void ffn_kernel(
    const float* __restrict__ x,
    const ushort_t* __restrict__ w1b_all, const float* __restrict__ b1,
    const ushort_t* __restrict__ w2b_all, const float* __restrict__ b2,
    const float* __restrict__ gamma, const float* __restrict__ beta,
    const int* __restrict__ counts, const ushort_t* __restrict__ lists,
    float* __restrict__ out)
{
  const int id = blockIdx.x;
  const int slot = id & 7;            // XCD affinity: branch n -> XCDs {2n,2n+1}
  const int n = slot >> 1;
  const int tile = ((id >> 3) << 1) + (slot & 1);
  const int cnt = counts[n];
  const int tile0 = tile * 96;
  if (tile0 >= cnt) return;
  const int mvalid = min(96, cnt - tile0);

  // 64 KB: sW1 bufs at [0,16K),[16K,32K); sW2 bufs at [32K,48K),[48K,64K).
  // Prologue aliases the region as sX[96][256] bf16 (48 KB), XOR-swizzled.
  __shared__ __align__(16) ushort_t sWmem[32768];
  __shared__ __align__(16) ushort_t sH[96][40];
  __shared__ ushort_t sB1[DF];        // b1 as bf16 (exact for b1==0)
  __shared__ int s_idx[96];
  __shared__ float s_ps[2][96];
  __shared__ float s_pq[2][96];
  __shared__ float s_mu[96];
  __shared__ float s_rs[96];

  ushort_t (*sX)[256] = (ushort_t (*)[256])sWmem;

  const int tid  = threadIdx.x;
  const int wv   = tid >> 6;          // 0..5
  const int lane = tid & 63;
  const int q    = lane >> 4;
  const int lc   = lane & 15;
  const int fi   = wv & 1;            // GEMM1 f-sub (16 cols of the 32-chunk)
  const int mh   = wv >> 1;           // token third (32 rows), 0..2
  const int dh   = wv & 1;            // GEMM2 d-half (128 cols)

  const ushort_t* w1b = w1b_all + (size_t)n * DF * DM;
  const ushort_t* w2b = w2b_all + (size_t)n * DM * DF;

  if (tid < 96) {
    int i = tile0 + tid;
    s_idx[tid] = (int)lists[n * TOK + (i < cnt ? i : tile0)];
  }
  // stage b1 slice as bf16 (1024 vals): 256 threads x 4
  if (tid < 256) {
    f32x4 v = *(const f32x4*)(b1 + n * DF + tid * 4);
    uint2 p;
    p.x = pack2(v.x, v.y);
    p.y = pack2(v.z, v.w);
    *(uint2*)(sB1 + tid * 4) = p;
  }
  __syncthreads();

  // ---- stage X tile 96x256 fp32 -> bf16 into sX, 16B-granule XOR swizzle
  #pragma unroll
  for (int it = 0; it < 8; ++it) {
    int flat = it * 384 + tid;
    int r = flat >> 5;                 // 0..95
    int c8 = flat & 31;                // 16B granule (8 bf16)
    const float* xp = x + (size_t)s_idx[r] * DM + c8 * 8;
    f32x4 a = *(const f32x4*)xp;
    f32x4 c = *(const f32x4*)(xp + 4);
    u32x4 p;
    p.x = pack2(a.x, a.y); p.y = pack2(a.z, a.w);
    p.z = pack2(c.x, c.y); p.w = pack2(c.z, c.w);
    *(u32x4*)(&sX[r][(c8 ^ (r & 31)) * 8]) = p;
  }
  __syncthreads();

  // ---- X A-frags to regs: this wave's 32 tokens x K=256 (64 VGPR)
  bf16x8 xfrag[2][8];
  #pragma unroll
  for (int mi2 = 0; mi2 < 2; ++mi2)
    #pragma unroll
    for (int ks = 0; ks < 8; ++ks) {
      int row = mh * 32 + mi2 * 16 + lc;
      int g = (ks * 4 + q) ^ (row & 31);
      xfrag[mi2][ks] = *(const bf16x8*)(&sX[row][g * 8]);
    }
  __syncthreads();        // sX dead; weight bufs free

  // DMA issue for chunk fc1 into buffer fc1&1. 32 x 1KB segs over 6 waves
  // (waves 0-3: 3 segs each, waves 4-5: 2). Swizzles applied on global src:
  //  W1 granule: cp ^ (r&31)  (matches GEMM1 read)
  //  W2 granule: cp ^ (d&3) ^ ((d>>2)&3)  (2-way-free on GEMM2 read)
  auto issue_dma = [&](int fc1) {
    const int b = fc1 & 1;
    ushort_t* dW1 = sWmem + b * 8192;
    ushort_t* dW2 = sWmem + 16384 + b * 8192;
    const ushort_t* g1 = w1b + (size_t)(fc1 * 32) * DM;
    const ushort_t* g2 = w2b + fc1 * 32;
    #pragma unroll
    for (int j = 0; j < 3; ++j) {
      int i = wv + j * 6;
      if (i < 16) {
        int s = i * 64 + lane;
        int r1 = s >> 5, cp1 = s & 31;
        dma16(g1 + (size_t)r1 * DM + (size_t)(cp1 ^ (r1 & 31)) * 8, dW1 + i * 512);
        int d2 = s >> 2, cp2 = s & 3;
        int cps = cp2 ^ (d2 & 3) ^ ((d2 >> 2) & 3);
        dma16(g2 + (size_t)d2 * DF + (size_t)cps * 8, dW2 + i * 512);
      }
    }
  };

  issue_dma(0);

  f32x4 yacc[2][8];       // [mi2][di]: 32 tok x 128 d (64 AccVGPR)
  #pragma unroll
  for (int mi2 = 0; mi2 < 2; ++mi2)
    #pragma unroll
    for (int di = 0; di < 8; ++di)
      yacc[mi2][di] = (f32x4){0.f, 0.f, 0.f, 0.f};

  #pragma unroll 1
  for (int fc = 0; fc < 32; ++fc) {
    const int b = fc & 1;
    const ushort_t* cW1 = sWmem + b * 8192;
    const ushort_t* cW2 = sWmem + 16384 + b * 8192;

    // entry barrier: drain the chunk-old prefetch (covered), sync buffers
    __builtin_amdgcn_sched_barrier(0);
    __builtin_amdgcn_s_waitcnt(0x0070);     // vmcnt(0) lgkmcnt(0)
    __builtin_amdgcn_s_barrier();
    __builtin_amdgcn_sched_barrier(0);

    // prefetch next chunk into the other buffers (drains at NEXT entry)
    if (fc < 31) issue_dma(fc + 1);

    const float b1v = bf2f(sB1[fc * 32 + fi * 16 + lc]);   // LDS, no vm op

    // ---- GEMM1: H[32 tok x 16 f] over K=256; B-frags reused over 2 mi2
    f32x4 hacc0 = (f32x4){0.f, 0.f, 0.f, 0.f};
    f32x4 hacc1 = (f32x4){0.f, 0.f, 0.f, 0.f};
    {
      const int r = fi * 16 + lc;           // W1 local row
      const ushort_t* w1row = cW1 + r * 256;
      __builtin_amdgcn_s_setprio(1);
      #pragma unroll
      for (int ks = 0; ks < 8; ++ks) {
        int cp = (ks * 4 + q) ^ (r & 31);
        bf16x8 bf = *(const bf16x8*)(w1row + cp * 8);
        hacc0 = __builtin_amdgcn_mfma_f32_16x16x32_bf16(xfrag[0][ks], bf, hacc0, 0, 0, 0);
        hacc1 = __builtin_amdgcn_mfma_f32_16x16x32_bf16(xfrag[1][ks], bf, hacc1, 0, 0, 0);
      }
      __builtin_amdgcn_s_setprio(0);
    }
    // ---- bias + ELU -> sH (C-layout -> row-major)
    #pragma unroll
    for (int r4 = 0; r4 < 4; ++r4) {
      float v0 = hacc0[r4] + b1v;
      v0 = (v0 > 0.f) ? v0 : (__expf(v0) - 1.f);
      sH[mh * 32 + q * 4 + r4][fi * 16 + lc] = f2bf(v0);
      float v1 = hacc1[r4] + b1v;
      v1 = (v1 > 0.f) ? v1 : (__expf(v1) - 1.f);
      sH[mh * 32 + 16 + q * 4 + r4][fi * 16 + lc] = f2bf(v1);
    }

    // mid barrier: publish sH; do NOT drain vmcnt (prefetch stays in flight)
    __builtin_amdgcn_sched_barrier(0);
    __builtin_amdgcn_s_waitcnt(0xC07F);     // lgkmcnt(0), vmcnt untouched
    __builtin_amdgcn_s_barrier();
    __builtin_amdgcn_sched_barrier(0);

    // ---- GEMM2: Y[32 tok x 128 d] += H[32 x 32] @ W2^T; B reused over 2 mi2
    bf16x8 af[2];
    #pragma unroll
    for (int mi2 = 0; mi2 < 2; ++mi2)
      af[mi2] = *(const bf16x8*)(&sH[mh * 32 + mi2 * 16 + lc][q * 8]);
    {
      const int cpw = (q ^ (lc & 3) ^ (lc >> 2)) * 8;   // = q^(d&3)^((d>>2)&3)
      const ushort_t* w2base = cW2 + (size_t)(dh * 128 + lc) * 32 + cpw;
      __builtin_amdgcn_s_setprio(1);
      #pragma unroll
      for (int di = 0; di < 8; ++di) {
        bf16x8 bf = *(const bf16x8*)(w2base + di * 512);
        yacc[0][di] = __builtin_amdgcn_mfma_f32_16x16x32_bf16(af[0], bf, yacc[0][di], 0, 0, 0);
        yacc[1][di] = __builtin_amdgcn_mfma_f32_16x16x32_bf16(af[1], bf, yacc[1][di], 0, 0, 0);
      }
      __builtin_amdgcn_s_setprio(0);
    }
  }

  // ================= epilogue: +b2, LN stats, gamma/beta, store =============
  __syncthreads();
  float b2v[8], gv[8], bv[8];
  #pragma unroll
  for (int di = 0; di < 8; ++di) {
    int dcol = n * DM + dh * 128 + di * 16 + lc;
    b2v[di] = b2[dcol];
    gv[di]  = gamma[dcol];
    bv[di]  = beta[dcol];
  }
  #pragma unroll
  for (int mi2 = 0; mi2 < 2; ++mi2)
    #pragma unroll
    for (int di = 0; di < 8; ++di)
      #pragma unroll
      for (int r4 = 0; r4 < 4; ++r4)
        yacc[mi2][di][r4] += b2v[di];

  #pragma unroll
  for (int mi2 = 0; mi2 < 2; ++mi2) {
    #pragma unroll
    for (int r4 = 0; r4 < 4; ++r4) {
      float s = 0.f, sq = 0.f;
      #pragma unroll
      for (int di = 0; di < 8; ++di) {
        float v = yacc[mi2][di][r4];
        s += v; sq += v * v;
      }
      #pragma unroll
      for (int off = 1; off < 16; off <<= 1) {
        s  += __shfl_xor(s, off, 64);
        sq += __shfl_xor(sq, off, 64);
      }
      if (lc == 0) {
        int tok = mh * 32 + mi2 * 16 + q * 4 + r4;
        s_ps[dh][tok] = s;
        s_pq[dh][tok] = sq;
      }
    }
  }
  __syncthreads();
  if (tid < 96) {
    float s  = s_ps[0][tid] + s_ps[1][tid];
    float sq = s_pq[0][tid] + s_pq[1][tid];
    float mu = s * (1.f / 256.f);
    float var = fmaxf(sq * (1.f / 256.f) - mu * mu, 0.f);
    s_mu[tid] = mu;
    s_rs[tid] = rsqrtf(var + 1e-12f);
  }
  __syncthreads();

  #pragma unroll
  for (int mi2 = 0; mi2 < 2; ++mi2) {
    #pragma unroll
    for (int r4 = 0; r4 < 4; ++r4) {
      int tok = mh * 32 + mi2 * 16 + q * 4 + r4;
      if (tok < mvalid) {
        float mu = s_mu[tok], rs = s_rs[tok];
        size_t rowbase = (size_t)s_idx[tok] * DM + dh * 128;
        #pragma unroll
        for (int di = 0; di < 8; ++di) {
          float v = (yacc[mi2][di][r4] - mu) * rs * gv[di] + bv[di];
          out[rowbase + di * 16 + lc] = v;
        }
      }
    }
  }
}

extern "C" void kernel_launch(void* const* d_in, const int* in_sizes, int n_in,
                              void* d_out, int out_size, void* d_ws, size_t ws_size,
                              hipStream_t stream) {
  const float* x     = (const float*)d_in[0];
  const int*   b_seq = (const int*)d_in[1];
  const float* w1    = (const float*)d_in[2];
  const float* b1    = (const float*)d_in[3];
  const float* w2    = (const float*)d_in[4];
  const float* b2    = (const float*)d_in[5];
  const float* gamma = (const float*)d_in[6];
  const float* beta  = (const float*)d_in[7];
  float* out = (float*)d_out;

  int* counts = (int*)d_ws;
  ushort_t* lists = (ushort_t*)((char*)d_ws + 256);                 // 512 KB
  ushort_t* w1b = (ushort_t*)((char*)d_ws + 256 + 512 * 1024);      // 2 MB
  ushort_t* w2b = w1b + (size_t)NB * DF * DM;                       // 2 MB

  hipLaunchKernelGGL(prep_weights_kernel, dim3(1024, 2), dim3(256), 0, stream,
                     w1, w2, w1b, w2b, counts);
  hipLaunchKernelGGL(route_kernel, dim3(TOK / 256), dim3(256), 0, stream,
                     b_seq, counts, lists, (u32x4*)d_out);
  // 342*8 blocks: tile capacity 684*96 >= 65536 tokens per branch
  hipLaunchKernelGGL(ffn_kernel, dim3(2736), dim3(384), 0, stream,
                     x, w1b, b1, w2b, b2, gamma, beta, counts, lists, out);
}

// Round 3
// 228.357 us; speedup vs baseline: 1.7707x; 1.7707x over previous
//
#include <hip/hip_runtime.h>

#define TOK 65536
#define DM 256
#define DF 1024
#define NB 4

typedef unsigned short ushort_t;
typedef unsigned int uint32;

typedef __attribute__((ext_vector_type(8))) short bf16x8;
typedef __attribute__((ext_vector_type(4))) float f32x4;
typedef __attribute__((ext_vector_type(4))) uint32 u32x4;

__device__ inline ushort_t f2bf(float f) {
  union { float f; unsigned int u; } v; v.f = f;
  unsigned int u = v.u;
  unsigned int r = (u + 0x7FFFu + ((u >> 16) & 1u)) >> 16;
  return (ushort_t)r;
}
__device__ inline float bf2f(ushort_t u) {
  union { unsigned int u; float f; } v; v.u = ((uint32)u) << 16; return v.f;
}
__device__ inline uint32 pack2(float a, float b) {
  return (uint32)f2bf(a) | ((uint32)f2bf(b) << 16);
}

// async global->LDS DMA, 16 B/lane: LDS dest = wave-uniform base + lane*16.
__device__ __forceinline__ void dma16(const ushort_t* g, ushort_t* lds) {
  __builtin_amdgcn_global_load_lds(
      (const __attribute__((address_space(1))) unsigned int*)(const void*)g,
      (__attribute__((address_space(3))) unsigned int*)(void*)lds,
      16, 0, 0);
}

// ---------------- kernel 0: convert w1/w2 fp32 -> bf16 + zero counts --------
__global__ __launch_bounds__(256) void prep_weights_kernel(
    const float* __restrict__ w1, const float* __restrict__ w2,
    ushort_t* __restrict__ w1b, ushort_t* __restrict__ w2b,
    int* __restrict__ counts)
{
  if (blockIdx.x == 0 && blockIdx.y == 0 && threadIdx.x < NB)
    counts[threadIdx.x] = 0;
  const int idx = blockIdx.x * 256 + threadIdx.x;
  const float* src = blockIdx.y ? w2 : w1;
  ushort_t* dst = blockIdx.y ? w2b : w1b;
  f32x4 v = *(const f32x4*)(src + (size_t)idx * 4);
  uint2 p;
  p.x = pack2(v.x, v.y);
  p.y = pack2(v.z, v.w);
  *(uint2*)(dst + (size_t)idx * 4) = p;
}

// ---------------- kernel 1: route tokens to per-branch lists + zero-fill ----
__global__ __launch_bounds__(256) void route_kernel(
    const int* __restrict__ b_seq, int* __restrict__ counts,
    ushort_t* __restrict__ lists, u32x4* __restrict__ out16)
{
  __shared__ int s_lpos[NB];
  __shared__ int s_lbase[NB];
  __shared__ int s_b[256];
  const int tid = threadIdx.x;
  const int base = blockIdx.x * 256;
  const int token = base + tid;
  if (tid < NB) s_lpos[tid] = 0;
  __syncthreads();
  const int b = b_seq[token];
  s_b[tid] = b;
  int my = 0;
  if (b > 0) my = atomicAdd(&s_lpos[b - 1], 1);
  __syncthreads();
  if (tid < NB) s_lbase[tid] = atomicAdd(&counts[tid], s_lpos[tid]);
  __syncthreads();
  if (b > 0) lists[(b - 1) * TOK + s_lbase[b - 1] + my] = (ushort_t)token;
  // zero-fill rows with b==0, 16 B per store (64 u32x4 per row of 256 f32)
  const u32x4 z = (u32x4){0u, 0u, 0u, 0u};
  #pragma unroll 4
  for (int it = 0; it < 64; ++it) {
    int flat = it * 256 + tid;
    int tl = flat >> 6;          // wave-uniform row
    int j = flat & 63;
    if (s_b[tl] == 0) out16[(size_t)(base + tl) * 64 + j] = z;
  }
}

// ---------------- kernel 2: fused FFN + LN, pipelined DMA, raw barriers -----
// Block = 8 waves (512 thr), M=64 tokens, 32 chunks of F=32.
// Residency plan (the round-1 lesson: block residency is register-granular):
// per-wave state HALVED vs round 0 — xfrag[8]=32 VGPR, yacc[8]=32 AGPR,
// unified ~100-110 <= 128 cap from __launch_bounds__(512,4). LDS ~74.5 KB ->
// 2 blocks/CU -> 16 waves/CU (4/SIMD), 2x round 0.
// GEMM1: wave (fi=wv&1, mq=wv>>1) computes H[16 tok x 16 f] per chunk.
// GEMM2: wave (dh=wv&1, mq)       accumulates Y[16 tok x 128 d].
// Weights double-buffered in LDS via global_load_lds issued one chunk ahead;
// entry barrier drains vmcnt(0)+lgkmcnt(0); mid barrier drains lgkm only so
// the prefetch is never force-drained mid-chunk.
__global__ __launch_bounds__(512, 4) void ffn_kernel(
    const float* __restrict__ x,
    const ushort_t* __restrict__ w1b_all, const float* __restrict__ b1,
    const ushort_t* __restrict__ w2b_all, const float* __restrict__ b2,
    const float* __restrict__ gamma, const float* __restrict__ beta,
    const int* __restrict__ counts, const ushort_t* __restrict__ lists,
    float* __restrict__ out)
{
  const int id = blockIdx.x;
  const int slot = id & 7;            // XCD affinity: branch n -> XCDs {2n,2n+1}
  const int n = slot >> 1;
  const int tile = ((id >> 3) << 1) + (slot & 1);
  const int cnt = counts[n];
  const int tile0 = tile * 64;
  if (tile0 >= cnt) return;
  const int mvalid = min(64, cnt - tile0);

  // 64 KB: sW1 bufs at [0,16K),[16K,32K); sW2 bufs at [32K,48K),[48K,64K).
  // Prologue aliases the region as sX[64][256] bf16 (32 KB), XOR-swizzled.
  __shared__ __align__(16) ushort_t sWmem[32768];
  __shared__ __align__(16) ushort_t sH[64][40];
  __shared__ ushort_t sB1[DF];        // b1 as bf16 (exact for b1==0)
  __shared__ int s_idx[64];
  __shared__ float s_ps[2][64];
  __shared__ float s_pq[2][64];
  __shared__ float s_mu[64];
  __shared__ float s_rs[64];

  ushort_t (*sX)[256] = (ushort_t (*)[256])sWmem;

  const int tid  = threadIdx.x;
  const int wv   = tid >> 6;          // 0..7
  const int lane = tid & 63;
  const int q    = lane >> 4;
  const int lc   = lane & 15;
  const int fi   = wv & 1;            // GEMM1 f-sub (16 cols of the 32-chunk)
  const int mq   = wv >> 1;           // token quarter (16 rows), 0..3
  const int dh   = wv & 1;            // GEMM2 d-half (128 cols)

  const ushort_t* w1b = w1b_all + (size_t)n * DF * DM;
  const ushort_t* w2b = w2b_all + (size_t)n * DM * DF;

  if (tid < 64) {
    int i = tile0 + tid;
    s_idx[tid] = (int)lists[n * TOK + (i < cnt ? i : tile0)];
  }
  // stage b1 slice as bf16 (1024 vals): 256 threads x 4
  if (tid < 256) {
    f32x4 v = *(const f32x4*)(b1 + n * DF + tid * 4);
    uint2 p;
    p.x = pack2(v.x, v.y);
    p.y = pack2(v.z, v.w);
    *(uint2*)(sB1 + tid * 4) = p;
  }
  __syncthreads();

  // ---- stage X tile 64x256 fp32 -> bf16 into sX, 16B-granule XOR swizzle
  #pragma unroll
  for (int it = 0; it < 4; ++it) {
    int flat = it * 512 + tid;
    int r = flat >> 5;                 // 0..63
    int c8 = flat & 31;                // 16B granule (8 bf16)
    const float* xp = x + (size_t)s_idx[r] * DM + c8 * 8;
    f32x4 a = *(const f32x4*)xp;
    f32x4 c = *(const f32x4*)(xp + 4);
    u32x4 p;
    p.x = pack2(a.x, a.y); p.y = pack2(a.z, a.w);
    p.z = pack2(c.x, c.y); p.w = pack2(c.z, c.w);
    *(u32x4*)(&sX[r][(c8 ^ (r & 31)) * 8]) = p;
  }
  __syncthreads();

  // ---- X A-frags to regs: this wave's 16 tokens x K=256 (32 VGPR)
  bf16x8 xfrag[8];
  #pragma unroll
  for (int ks = 0; ks < 8; ++ks) {
    int row = mq * 16 + lc;
    int g = (ks * 4 + q) ^ (row & 31);
    xfrag[ks] = *(const bf16x8*)(&sX[row][g * 8]);
  }
  __syncthreads();        // sX dead; weight bufs free

  // DMA issue for chunk fc1 into buffer fc1&1. 32 x 1KB segs over 8 waves
  // (2 W1 + 2 W2 per wave). Swizzles applied on global src:
  //  W1 granule: cp ^ (r&31)             (matches GEMM1 read)
  //  W2 granule: cp ^ (d&3) ^ ((d>>2)&3) (matches GEMM2 read)
  auto issue_dma = [&](int fc1) {
    const int b = fc1 & 1;
    ushort_t* dW1 = sWmem + b * 8192;
    ushort_t* dW2 = sWmem + 16384 + b * 8192;
    const ushort_t* g1 = w1b + (size_t)(fc1 * 32) * DM;
    const ushort_t* g2 = w2b + fc1 * 32;
    #pragma unroll
    for (int j = 0; j < 2; ++j) {
      int i = wv * 2 + j;              // 0..15
      int s = i * 64 + lane;
      int r1 = s >> 5, cp1 = s & 31;
      dma16(g1 + (size_t)r1 * DM + (size_t)(cp1 ^ (r1 & 31)) * 8, dW1 + i * 512);
      int d2 = s >> 2, cp2 = s & 3;
      int cps = cp2 ^ (d2 & 3) ^ ((d2 >> 2) & 3);
      dma16(g2 + (size_t)d2 * DF + (size_t)cps * 8, dW2 + i * 512);
    }
  };

  issue_dma(0);

  f32x4 yacc[8];          // [di]: 16 tok x 128 d (32 AccVGPR)
  #pragma unroll
  for (int di = 0; di < 8; ++di)
    yacc[di] = (f32x4){0.f, 0.f, 0.f, 0.f};

  #pragma unroll 1
  for (int fc = 0; fc < 32; ++fc) {
    const int b = fc & 1;
    const ushort_t* cW1 = sWmem + b * 8192;
    const ushort_t* cW2 = sWmem + 16384 + b * 8192;

    // entry barrier: drain the chunk-old prefetch (covered), sync buffers
    __builtin_amdgcn_sched_barrier(0);
    __builtin_amdgcn_s_waitcnt(0x0070);     // vmcnt(0) lgkmcnt(0)
    __builtin_amdgcn_s_barrier();
    __builtin_amdgcn_sched_barrier(0);

    // prefetch next chunk into the other buffers (drains at NEXT entry)
    if (fc < 31) issue_dma(fc + 1);

    const float b1v = bf2f(sB1[fc * 32 + fi * 16 + lc]);   // LDS, no vm op

    // ---- GEMM1: H[16 tok x 16 f] over K=256, two interleaved half-K chains
    f32x4 ha = (f32x4){0.f, 0.f, 0.f, 0.f};
    f32x4 hb = (f32x4){0.f, 0.f, 0.f, 0.f};
    {
      const int r = fi * 16 + lc;           // W1 local row (0..31)
      const ushort_t* w1row = cW1 + r * 256;
      __builtin_amdgcn_s_setprio(1);
      #pragma unroll
      for (int ks = 0; ks < 4; ++ks) {
        int cpa = ((2 * ks) * 4 + q) ^ r;
        int cpb = ((2 * ks + 1) * 4 + q) ^ r;
        bf16x8 bfa = *(const bf16x8*)(w1row + cpa * 8);
        bf16x8 bfb = *(const bf16x8*)(w1row + cpb * 8);
        ha = __builtin_amdgcn_mfma_f32_16x16x32_bf16(xfrag[2 * ks],     bfa, ha, 0, 0, 0);
        hb = __builtin_amdgcn_mfma_f32_16x16x32_bf16(xfrag[2 * ks + 1], bfb, hb, 0, 0, 0);
      }
      __builtin_amdgcn_s_setprio(0);
    }
    // ---- bias + ELU -> sH (C-layout -> row-major)
    #pragma unroll
    for (int r4 = 0; r4 < 4; ++r4) {
      float v = ha[r4] + hb[r4] + b1v;
      v = (v > 0.f) ? v : (__expf(v) - 1.f);
      sH[mq * 16 + q * 4 + r4][fi * 16 + lc] = f2bf(v);
    }

    // mid barrier: publish sH; do NOT drain vmcnt (prefetch stays in flight)
    __builtin_amdgcn_sched_barrier(0);
    __builtin_amdgcn_s_waitcnt(0xC07F);     // lgkmcnt(0), vmcnt untouched
    __builtin_amdgcn_s_barrier();
    __builtin_amdgcn_sched_barrier(0);

    // ---- GEMM2: Y[16 tok x 128 d] += H[16 x 32] @ W2^T; 8 indep chains
    {
      bf16x8 af = *(const bf16x8*)(&sH[mq * 16 + lc][q * 8]);
      const int cpw = (q ^ (lc & 3) ^ ((lc >> 2) & 3)) * 8;
      const ushort_t* w2base = cW2 + (size_t)(dh * 128 + lc) * 32 + cpw;
      __builtin_amdgcn_s_setprio(1);
      #pragma unroll
      for (int di = 0; di < 8; ++di) {
        bf16x8 bf = *(const bf16x8*)(w2base + di * 512);
        yacc[di] = __builtin_amdgcn_mfma_f32_16x16x32_bf16(af, bf, yacc[di], 0, 0, 0);
      }
      __builtin_amdgcn_s_setprio(0);
    }
  }

  // ================= epilogue: +b2, LN stats, gamma/beta, store =============
  __syncthreads();
  float b2v[8], gv[8], bv[8];
  #pragma unroll
  for (int di = 0; di < 8; ++di) {
    int dcol = n * DM + dh * 128 + di * 16 + lc;
    b2v[di] = b2[dcol];
    gv[di]  = gamma[dcol];
    bv[di]  = beta[dcol];
  }
  #pragma unroll
  for (int di = 0; di < 8; ++di)
    #pragma unroll
    for (int r4 = 0; r4 < 4; ++r4)
      yacc[di][r4] += b2v[di];

  #pragma unroll
  for (int r4 = 0; r4 < 4; ++r4) {
    float s = 0.f, sq = 0.f;
    #pragma unroll
    for (int di = 0; di < 8; ++di) {
      float v = yacc[di][r4];
      s += v; sq += v * v;
    }
    #pragma unroll
    for (int off = 1; off < 16; off <<= 1) {
      s  += __shfl_xor(s, off, 64);
      sq += __shfl_xor(sq, off, 64);
    }
    if (lc == 0) {
      int tok = mq * 16 + q * 4 + r4;
      s_ps[dh][tok] = s;
      s_pq[dh][tok] = sq;
    }
  }
  __syncthreads();
  if (tid < 64) {
    float s  = s_ps[0][tid] + s_ps[1][tid];
    float sq = s_pq[0][tid] + s_pq[1][tid];
    float mu = s * (1.f / 256.f);
    float var = fmaxf(sq * (1.f / 256.f) - mu * mu, 0.f);
    s_mu[tid] = mu;
    s_rs[tid] = rsqrtf(var + 1e-12f);
  }
  __syncthreads();

  #pragma unroll
  for (int r4 = 0; r4 < 4; ++r4) {
    int tok = mq * 16 + q * 4 + r4;
    if (tok < mvalid) {
      float mu = s_mu[tok], rs = s_rs[tok];
      size_t rowbase = (size_t)s_idx[tok] * DM + dh * 128;
      #pragma unroll
      for (int di = 0; di < 8; ++di) {
        float v = (yacc[di][r4] - mu) * rs * gv[di] + bv[di];
        out[rowbase + di * 16 + lc] = v;
      }
    }
  }
}

extern "C" void kernel_launch(void* const* d_in, const int* in_sizes, int n_in,
                              void* d_out, int out_size, void* d_ws, size_t ws_size,
                              hipStream_t stream) {
  const float* x     = (const float*)d_in[0];
  const int*   b_seq = (const int*)d_in[1];
  const float* w1    = (const float*)d_in[2];
  const float* b1    = (const float*)d_in[3];
  const float* w2    = (const float*)d_in[4];
  const float* b2    = (const float*)d_in[5];
  const float* gamma = (const float*)d_in[6];
  const float* beta  = (const float*)d_in[7];
  float* out = (float*)d_out;

  int* counts = (int*)d_ws;
  ushort_t* lists = (ushort_t*)((char*)d_ws + 256);                 // 512 KB
  ushort_t* w1b = (ushort_t*)((char*)d_ws + 256 + 512 * 1024);      // 2 MB
  ushort_t* w2b = w1b + (size_t)NB * DF * DM;                       // 2 MB

  hipLaunchKernelGGL(prep_weights_kernel, dim3(1024, 2), dim3(256), 0, stream,
                     w1, w2, w1b, w2b, counts);
  hipLaunchKernelGGL(route_kernel, dim3(TOK / 256), dim3(256), 0, stream,
                     b_seq, counts, lists, (u32x4*)d_out);
  // 1024 tiles/branch capacity: covers any branch imbalance up to 65536
  hipLaunchKernelGGL(ffn_kernel, dim3(4096), dim3(512), 0, stream,
                     x, w1b, b1, w2b, b2, gamma, beta, counts, lists, out);
}